// Round 2
// baseline (81309.576 us; speedup 1.0000x reference)
//
#include <hip/hip_runtime.h>
#include <cstdint>
#include <cstddef>

// ============================================================================
// PointerNet: encoder LSTM (B=512,S=256,D=2,H=256) + autoregressive pointer
// decode with jax.random.categorical (threefry2x32 partitionable, key 42).
// Output: int32 indices [512][256], trajectory-exact vs JAX reference.
//
// R6: R4 operand structure (broadcast-LDS; R5's readlane regressed +1.33ms =
// exactly its added VALU issue -> time ~ serial issue+latency path), plus:
//  * decoder schedule rotated: attention loads for step t (L3-resident encK4,
//    ~700cy each, previously a serial latency wall after P2) are issued and
//    consumed INTERLEAVED with the NEXT step's Wh.h sweep (both only need
//    h_t). 3-deep 4xv4f register pipeline per thread.
//  * 4 barriers/decoder step (R5's verified partV/partI staging merge kept).
//  * FMA accumulation order identical to R4 -> bit-identical trajectory.
// ============================================================================

typedef float v4f __attribute__((ext_vector_type(4)));

#define WS_ENCW4_OFF  (2u << 20)                    // [256 k][256 u][4 g] f32
#define WS_DECWI4_OFF (3u << 20)
#define WS_DECWH4_OFF (4u << 20)
#define WS_ENCK4_OFF  (5u << 20)                    // [512 b][64 u4][256 s][4] f32
#define WS_NEEDED     ((size_t)(5u << 20) + (size_t)512 * 64 * 256 * 16)

__device__ __forceinline__ unsigned rotl32(unsigned x, int r) {
  return (x << r) | (x >> (32 - r));
}
__device__ __forceinline__ float sigm(float x) { return 1.f / (1.f + expf(-x)); }

// Threefry-2x32, 20 rounds (jax._src.prng schedule) — verified exact R1-R5.
__device__ __forceinline__ void tf2(unsigned k0, unsigned k1,
                                    unsigned& x0, unsigned& x1) {
  const unsigned k2 = k0 ^ k1 ^ 0x1BD11BDAu;
  x0 += k0; x1 += k1;
  x0 += x1; x1 = rotl32(x1, 13); x1 ^= x0;
  x0 += x1; x1 = rotl32(x1, 15); x1 ^= x0;
  x0 += x1; x1 = rotl32(x1, 26); x1 ^= x0;
  x0 += x1; x1 = rotl32(x1,  6); x1 ^= x0;
  x0 += k1; x1 += k2 + 1u;
  x0 += x1; x1 = rotl32(x1, 17); x1 ^= x0;
  x0 += x1; x1 = rotl32(x1, 29); x1 ^= x0;
  x0 += x1; x1 = rotl32(x1, 16); x1 ^= x0;
  x0 += x1; x1 = rotl32(x1, 24); x1 ^= x0;
  x0 += k2; x1 += k0 + 2u;
  x0 += x1; x1 = rotl32(x1, 13); x1 ^= x0;
  x0 += x1; x1 = rotl32(x1, 15); x1 ^= x0;
  x0 += x1; x1 = rotl32(x1, 26); x1 ^= x0;
  x0 += x1; x1 = rotl32(x1,  6); x1 ^= x0;
  x0 += k0; x1 += k1 + 3u;
  x0 += x1; x1 = rotl32(x1, 17); x1 ^= x0;
  x0 += x1; x1 = rotl32(x1, 29); x1 ^= x0;
  x0 += x1; x1 = rotl32(x1, 16); x1 ^= x0;
  x0 += x1; x1 = rotl32(x1, 24); x1 ^= x0;
  x0 += k1; x1 += k2 + 4u;
  x0 += x1; x1 = rotl32(x1, 13); x1 ^= x0;
  x0 += x1; x1 = rotl32(x1, 15); x1 ^= x0;
  x0 += x1; x1 = rotl32(x1, 26); x1 ^= x0;
  x0 += x1; x1 = rotl32(x1,  6); x1 ^= x0;
  x0 += k2; x1 += k0 + 5u;
}

// Repack W [1024 rows][256 k] row-major -> [k][u][gate] (float4 per (k,u)).
__global__ void repack_k(const float* __restrict__ eWh,
                         const float* __restrict__ dWi,
                         const float* __restrict__ dWh,
                         float* __restrict__ ws) {
  float* encW4 = (float*)((char*)ws + WS_ENCW4_OFF);
  float* decWi4 = (float*)((char*)ws + WS_DECWI4_OFF);
  float* decWh4 = (float*)((char*)ws + WS_DECWH4_OFF);
  const int n = blockIdx.x * blockDim.x + threadIdx.x;   // 65536 = 256k x 256u
  if (n >= 65536) return;
  const int k = n >> 8, u = n & 255;
#pragma unroll
  for (int g = 0; g < 4; ++g) {
    const int src = ((g << 8) + u) * 256 + k;
    const int dst = (n << 2) + g;
    encW4[dst] = eWh[src];
    decWi4[dst] = dWi[src];
    decWh4[dst] = dWh[src];
  }
}

__global__ void __launch_bounds__(1024)
ptrnet_kernel(const float* __restrict__ inp,    // [512][256][2]
              const float* __restrict__ eWi,    // [1024][2]
              const float* __restrict__ eBi, const float* __restrict__ eBh,
              const float* __restrict__ dBi, const float* __restrict__ dBh,
              int* __restrict__ out,            // [512][256]
              float* __restrict__ ws) {
  const int tid  = threadIdx.x;
  const int wave = tid >> 6, l = tid & 63;
  const int kq   = wave >> 2;               // K-quarter 0..3 (16 k4 each)
  const int uw   = wave & 3;                // u-slice 0..3
  const int uP   = (uw << 6) | l;           // this lane's unit in P1 (matmul)
  const int k4b  = kq << 4;
  const int bA   = tid >> 8;                // this thread's batch in P2/attn
  const int uA   = tid & 255;               // this thread's unit/score in P2/attn
  const int b0   = blockIdx.x << 2;
  const int bG   = b0 + bA;

  const v4f* encW4  = (const v4f*)((char*)ws + WS_ENCW4_OFF);
  const v4f* decWi4 = (const v4f*)((char*)ws + WS_DECWI4_OFF);
  const v4f* decWh4 = (const v4f*)((char*)ws + WS_DECWH4_OFF);
  v4f* encK4 = (v4f*)((char*)ws + WS_ENCK4_OFF);

  __shared__ __align__(16) float hsF[2][1024];   // h dbuf: [buf][b*256+u]
  __shared__ __align__(16) v4f dinV[256];        // dec_in [b][64 k4]
  __shared__ __align__(16) v4f red[16][256];     // partials [kq*4+b][u] (gates)
  __shared__ unsigned char maskC[4][256];
  __shared__ float partV[4][4];
  __shared__ int   partI[4][4];

  // ---- activation-thread constants (keyed by uA) ----
  const float ebi_ = eBi[uA] + eBh[uA];
  const float ebf_ = eBi[256 + uA] + eBh[256 + uA];
  const float ebg_ = eBi[512 + uA] + eBh[512 + uA];
  const float ebo_ = eBi[768 + uA] + eBh[768 + uA];
  const float wxi0 = eWi[2 * uA], wxi1 = eWi[2 * uA + 1];
  const float wxf0 = eWi[2 * (256 + uA)], wxf1 = eWi[2 * (256 + uA) + 1];
  const float wxg0 = eWi[2 * (512 + uA)], wxg1 = eWi[2 * (512 + uA) + 1];
  const float wxo0 = eWi[2 * (768 + uA)], wxo1 = eWi[2 * (768 + uA) + 1];

  hsF[0][tid] = 0.f;
  __syncthreads();

  float c = 0.f;        // cell state for (bG, uA) — register-resident throughout
  int p = 0;

  // ---------------- encoder: 256 steps (R4-exact) ----------------
  for (int t = 0; t < 256; ++t) {
    v4f a0 = (v4f)0.f, a1 = (v4f)0.f, a2 = (v4f)0.f, a3 = (v4f)0.f;
    const v4f* Wp = encW4 + uP;
    const v4f* hq = (const v4f*)&hsF[p][0];       // [4 b][64 k4]
#pragma unroll 2
    for (int kk = 0; kk < 16; ++kk) {
      const int k4 = k4b + kk;
      const v4f w0 = Wp[(k4 * 4 + 0) << 8];
      const v4f w1 = Wp[(k4 * 4 + 1) << 8];
      const v4f w2 = Wp[(k4 * 4 + 2) << 8];
      const v4f w3 = Wp[(k4 * 4 + 3) << 8];
      const v4f h0 = hq[k4];
      const v4f h1 = hq[64 + k4];
      const v4f h2 = hq[128 + k4];
      const v4f h3 = hq[192 + k4];
      a0 += w0 * h0.x + w1 * h0.y + w2 * h0.z + w3 * h0.w;
      a1 += w0 * h1.x + w1 * h1.y + w2 * h1.z + w3 * h1.w;
      a2 += w0 * h2.x + w1 * h2.y + w2 * h2.z + w3 * h2.w;
      a3 += w0 * h3.x + w1 * h3.y + w2 * h3.z + w3 * h3.w;
    }
    red[(kq << 2) | 0][uP] = a0;
    red[(kq << 2) | 1][uP] = a1;
    red[(kq << 2) | 2][uP] = a2;
    red[(kq << 2) | 3][uP] = a3;
    __syncthreads();                              // S_B: partials ready
    const v4f gv = red[bA][uA] + red[4 + bA][uA] + red[8 + bA][uA] + red[12 + bA][uA];
    const float2 xv = *(const float2*)(inp + (((bG) << 8) + t) * 2);
    const float ai = gv.x + ebi_ + wxi0 * xv.x + wxi1 * xv.y;
    const float af = gv.y + ebf_ + wxf0 * xv.x + wxf1 * xv.y;
    const float ag = gv.z + ebg_ + wxg0 * xv.x + wxg1 * xv.y;
    const float ao = gv.w + ebo_ + wxo0 * xv.x + wxo1 * xv.y;
    const float iv = sigm(ai), fv = sigm(af), gva = tanhf(ag), ov = sigm(ao);
    c = fv * c + iv * gva;
    const float hn = ov * tanhf(c);
    hsF[p ^ 1][(bA << 8) | uA] = hn;
    ((float*)encK4)[(((bG << 6) + (uA >> 2)) << 10) + (t << 2) + (uA & 3)] = hn;
    __syncthreads();                              // S_C: new h ready
    p ^= 1;
  }

  // ---------------- decoder: 256 steps, rotated schedule ----------------
  const float dbi_ = dBi[uA] + dBh[uA];
  const float dbf_ = dBi[256 + uA] + dBh[256 + uA];
  const float dbg_ = dBi[512 + uA] + dBh[512 + uA];
  const float dbo_ = dBi[768 + uA] + dBh[768 + uA];
  const float NEG_INF = __int_as_float((int)0xff800000);

  maskC[bA][uA] = 0;
  if (tid < 256) dinV[tid] = (v4f)0.f;
  __syncthreads();

  // ---- prologue: LSTM step 0 (din = 0 -> Wi contributes exact 0, skipped) ----
  {
    v4f a0 = (v4f)0.f, a1 = (v4f)0.f, a2 = (v4f)0.f, a3 = (v4f)0.f;
    const v4f* Wh = decWh4 + uP;
    const v4f* hq = (const v4f*)&hsF[p][0];
#pragma unroll 2
    for (int kk = 0; kk < 16; ++kk) {
      const int k4 = k4b + kk;
      const v4f w0 = Wh[(k4 * 4 + 0) << 8];
      const v4f w1 = Wh[(k4 * 4 + 1) << 8];
      const v4f w2 = Wh[(k4 * 4 + 2) << 8];
      const v4f w3 = Wh[(k4 * 4 + 3) << 8];
      const v4f h0 = hq[k4];
      const v4f h1 = hq[64 + k4];
      const v4f h2 = hq[128 + k4];
      const v4f h3 = hq[192 + k4];
      a0 += w0 * h0.x + w1 * h0.y + w2 * h0.z + w3 * h0.w;
      a1 += w0 * h1.x + w1 * h1.y + w2 * h1.z + w3 * h1.w;
      a2 += w0 * h2.x + w1 * h2.y + w2 * h2.z + w3 * h2.w;
      a3 += w0 * h3.x + w1 * h3.y + w2 * h3.z + w3 * h3.w;
    }
    red[(kq << 2) | 0][uP] = a0;
    red[(kq << 2) | 1][uP] = a1;
    red[(kq << 2) | 2][uP] = a2;
    red[(kq << 2) | 3][uP] = a3;
    __syncthreads();
    const v4f gv = red[bA][uA] + red[4 + bA][uA] + red[8 + bA][uA] + red[12 + bA][uA];
    const float iv = sigm(gv.x + dbi_), fv = sigm(gv.y + dbf_);
    const float gva = tanhf(gv.z + dbg_), ov = sigm(gv.w + dbo_);
    c = fv * c + iv * gva;
    const float hn = ov * tanhf(c);
    hsF[p ^ 1][(bA << 8) | uA] = hn;
    __syncthreads();
    p ^= 1;                                       // hsF[p] now holds h_0
  }

  for (int t = 0; t < 256; ++t) {
    // ---- overlap phase: attn(t) loads+consume  ∥  Wh·h_t sweep (for t+1) ----
    const int masked = maskC[bA][uA];
    const v4f* E   = encK4 + (bG << 14) + uA;     // s = uA, step u4 via <<8
    const v4f* hq  = (const v4f*)&hsF[p][0];
    const v4f* hq2 = hq + (bA << 6);
    const v4f* Wh  = decWh4 + uP;
    v4f a0 = (v4f)0.f, a1 = (v4f)0.f, a2 = (v4f)0.f, a3 = (v4f)0.f;
    float sc = 0.f;
    v4f eA[3][4];                                  // 3 chunks x 4 k4 in flight
    if (!masked) {
#pragma unroll
      for (int j = 0; j < 4; ++j) eA[0][j] = E[j << 8];
#pragma unroll
      for (int j = 0; j < 4; ++j) eA[1][j] = E[(4 + j) << 8];
    }
#pragma unroll
    for (int ph = 0; ph < 16; ++ph) {
      // Wh iteration kk = ph (same expression/order as R4 -> bit-identical a)
      {
        const int k4 = k4b + ph;
        const v4f w0 = Wh[(k4 * 4 + 0) << 8];
        const v4f w1 = Wh[(k4 * 4 + 1) << 8];
        const v4f w2 = Wh[(k4 * 4 + 2) << 8];
        const v4f w3 = Wh[(k4 * 4 + 3) << 8];
        const v4f h0 = hq[k4];
        const v4f h1 = hq[64 + k4];
        const v4f h2 = hq[128 + k4];
        const v4f h3 = hq[192 + k4];
        a0 += w0 * h0.x + w1 * h0.y + w2 * h0.z + w3 * h0.w;
        a1 += w0 * h1.x + w1 * h1.y + w2 * h1.z + w3 * h1.w;
        a2 += w0 * h2.x + w1 * h2.y + w2 * h2.z + w3 * h2.w;
        a3 += w0 * h3.x + w1 * h3.y + w2 * h3.z + w3 * h3.w;
      }
      // issue attn chunk ph+2
      if (ph < 14) {
        if (!masked) {
#pragma unroll
          for (int j = 0; j < 4; ++j) eA[(ph + 2) % 3][j] = E[((ph + 2) * 4 + j) << 8];
        }
      }
      // consume attn chunk ph (sc chain order identical to R4's k4 order)
      if (!masked) {
#pragma unroll
        for (int j = 0; j < 4; ++j) {
          const int k4 = ph * 4 + j;
          const v4f ev = eA[ph % 3][j];
          const v4f hv = hq2[k4];
          sc += ev.x * hv.x + ev.y * hv.y + ev.z * hv.z + ev.w * hv.w;
        }
      }
    }

    // ---- gumbel + argmax (thread (bA, s=uA)) ----
    unsigned bits;
    {
      unsigned kk0 = 0u, kk1 = (unsigned)t;
      tf2(0u, 42u, kk0, kk1);
      unsigned y0 = 0u, y1 = (unsigned)((bG << 8) + uA);
      tf2(kk0, kk1, y0, y1);
      bits = y0 ^ y1;
    }
    const float fr = __uint_as_float((bits >> 9) | 0x3f800000u) - 1.0f;
    const float uu = (fr > 0.f) ? fr : 1.17549435e-38f;
    const float gum = -logf(-logf(uu));
    float bv = masked ? NEG_INF : (sc + gum);
    int bi = uA;
#pragma unroll
    for (int off = 32; off; off >>= 1) {
      const float ov2 = __shfl_xor(bv, off, 64);
      const int oi2 = __shfl_xor(bi, off, 64);
      if (ov2 > bv || (ov2 == bv && oi2 < bi)) { bv = ov2; bi = oi2; }
    }
    if (l == 0) { partV[bA][uw] = bv; partI[bA][uw] = bi; }
    __syncthreads();                              // S_D: wave partials ready

    // final cross-chunk argmax, recomputed redundantly per thread
    float v = partV[bA][0]; int fi = partI[bA][0];
#pragma unroll
    for (int j = 1; j < 4; ++j) {
      const float vj = partV[bA][j];
      if (vj > v) { v = vj; fi = partI[bA][j]; }   // strict > keeps lowest s
    }
    if (uA == 0) out[(bG << 8) + t] = fi;
    if (uA == fi) maskC[bA][uA] = 1;
    if (tid < 256) {                               // stage din_{t+1}
      const int bb = tid >> 6, k4s = tid & 63;
      float v2 = partV[bb][0]; int fib = partI[bb][0];
#pragma unroll
      for (int j = 1; j < 4; ++j) {
        const float vj = partV[bb][j];
        if (vj > v2) { v2 = vj; fib = partI[bb][j]; }
      }
      dinV[tid] = encK4[((((b0 + bb) << 6) | k4s) << 8) + fib];
    }
    __syncthreads();                              // S_A: din/mask ready

    if (t == 255) break;                           // last index emitted

    // ---- Wi·din sweep (adds into the SAME a-regs, R4 order) ----
    {
      const v4f* Wi = decWi4 + uP;
#pragma unroll 2
      for (int kk = 0; kk < 16; ++kk) {
        const int k4 = k4b + kk;
        const v4f w0 = Wi[(k4 * 4 + 0) << 8];
        const v4f w1 = Wi[(k4 * 4 + 1) << 8];
        const v4f w2 = Wi[(k4 * 4 + 2) << 8];
        const v4f w3 = Wi[(k4 * 4 + 3) << 8];
        const v4f d0 = dinV[k4];
        const v4f d1 = dinV[64 + k4];
        const v4f d2 = dinV[128 + k4];
        const v4f d3 = dinV[192 + k4];
        a0 += w0 * d0.x + w1 * d0.y + w2 * d0.z + w3 * d0.w;
        a1 += w0 * d1.x + w1 * d1.y + w2 * d1.z + w3 * d1.w;
        a2 += w0 * d2.x + w1 * d2.y + w2 * d2.z + w3 * d2.w;
        a3 += w0 * d3.x + w1 * d3.y + w2 * d3.z + w3 * d3.w;
      }
    }
    red[(kq << 2) | 0][uP] = a0;
    red[(kq << 2) | 1][uP] = a1;
    red[(kq << 2) | 2][uP] = a2;
    red[(kq << 2) | 3][uP] = a3;
    __syncthreads();                              // S_B: partials ready

    // ---- P2: activation -> h_{t+1} ----
    const v4f gv = red[bA][uA] + red[4 + bA][uA] + red[8 + bA][uA] + red[12 + bA][uA];
    const float iv = sigm(gv.x + dbi_), fv = sigm(gv.y + dbf_);
    const float gva = tanhf(gv.z + dbg_), ov = sigm(gv.w + dbo_);
    c = fv * c + iv * gva;
    const float hn = ov * tanhf(c);
    hsF[p ^ 1][(bA << 8) | uA] = hn;
    __syncthreads();                              // S_C: new h ready
    p ^= 1;
  }
}

extern "C" void kernel_launch(void* const* d_in, const int* in_sizes, int n_in,
                              void* d_out, int out_size, void* d_ws, size_t ws_size,
                              hipStream_t stream) {
  (void)in_sizes; (void)n_in; (void)out_size;
  if (ws_size < WS_NEEDED) return;   // need ~139 MB scratch

  const float* inp = (const float*)d_in[0];
  const float* eWi = (const float*)d_in[1];
  const float* eWh = (const float*)d_in[2];
  const float* eBi = (const float*)d_in[3];
  const float* eBh = (const float*)d_in[4];
  const float* dWi = (const float*)d_in[5];
  const float* dWh = (const float*)d_in[6];
  const float* dBi = (const float*)d_in[7];
  const float* dBh = (const float*)d_in[8];
  int* out = (int*)d_out;
  float* wsf = (float*)d_ws;

  hipLaunchKernelGGL(repack_k, dim3(256), dim3(256), 0, stream, eWh, dWi, dWh, wsf);
  hipLaunchKernelGGL(ptrnet_kernel, dim3(128), dim3(1024), 0, stream,
                     inp, eWi, eBi, eBh, dBi, dBh, out, wsf);
}

// Round 3
// 80321.454 us; speedup vs baseline: 1.0123x; 1.0123x over previous
//
#include <hip/hip_runtime.h>
#include <cstdint>
#include <cstddef>

// ============================================================================
// PointerNet: encoder LSTM (B=512,S=256,D=2,H=256) + autoregressive pointer
// decode with jax.random.categorical (threefry2x32 partitionable, key 42).
// Output: int32 indices [512][256], trajectory-exact vs JAX reference.
//
// R7 = R6 + __launch_bounds__(1024, 4).
// R6's rotated schedule PASSED correctness but spilled: bare
// __launch_bounds__(1024) let the compiler target 2 blocks/CU (LDS 79KB < 80KB)
// -> 64-VGPR cap -> eA[3][4] attention pipeline (48 VGPRs) spilled to scratch
// (WRITE_SIZE 273MB -> 75.5GB, VALUBusy 33% -> 3.9%, dur 13ms -> 81ms).
// Grid is 128 blocks on 256 CUs: only 1 block/CU is ever resident, so the
// 2-block occupancy target was pure loss. (1024,4) = 4 waves/EU = 1 block/CU
// -> 128-VGPR budget; overlap-loop live set ~115 regs fits.
//  * decoder schedule rotated: attention loads for step t (L3/HBM encK4,
//    previously a serial latency wall after P2) issued+consumed INTERLEAVED
//    with the NEXT step's Wh.h sweep (both only need h_t). 3-deep 4xv4f
//    register pipeline per thread.
//  * 4 barriers/decoder step; FMA order identical to R4 -> exact trajectory.
// ============================================================================

typedef float v4f __attribute__((ext_vector_type(4)));

#define WS_ENCW4_OFF  (2u << 20)                    // [256 k][256 u][4 g] f32
#define WS_DECWI4_OFF (3u << 20)
#define WS_DECWH4_OFF (4u << 20)
#define WS_ENCK4_OFF  (5u << 20)                    // [512 b][64 u4][256 s][4] f32
#define WS_NEEDED     ((size_t)(5u << 20) + (size_t)512 * 64 * 256 * 16)

__device__ __forceinline__ unsigned rotl32(unsigned x, int r) {
  return (x << r) | (x >> (32 - r));
}
__device__ __forceinline__ float sigm(float x) { return 1.f / (1.f + expf(-x)); }

// Threefry-2x32, 20 rounds (jax._src.prng schedule) — verified exact R1-R6.
__device__ __forceinline__ void tf2(unsigned k0, unsigned k1,
                                    unsigned& x0, unsigned& x1) {
  const unsigned k2 = k0 ^ k1 ^ 0x1BD11BDAu;
  x0 += k0; x1 += k1;
  x0 += x1; x1 = rotl32(x1, 13); x1 ^= x0;
  x0 += x1; x1 = rotl32(x1, 15); x1 ^= x0;
  x0 += x1; x1 = rotl32(x1, 26); x1 ^= x0;
  x0 += x1; x1 = rotl32(x1,  6); x1 ^= x0;
  x0 += k1; x1 += k2 + 1u;
  x0 += x1; x1 = rotl32(x1, 17); x1 ^= x0;
  x0 += x1; x1 = rotl32(x1, 29); x1 ^= x0;
  x0 += x1; x1 = rotl32(x1, 16); x1 ^= x0;
  x0 += x1; x1 = rotl32(x1, 24); x1 ^= x0;
  x0 += k2; x1 += k0 + 2u;
  x0 += x1; x1 = rotl32(x1, 13); x1 ^= x0;
  x0 += x1; x1 = rotl32(x1, 15); x1 ^= x0;
  x0 += x1; x1 = rotl32(x1, 26); x1 ^= x0;
  x0 += x1; x1 = rotl32(x1,  6); x1 ^= x0;
  x0 += k0; x1 += k1 + 3u;
  x0 += x1; x1 = rotl32(x1, 17); x1 ^= x0;
  x0 += x1; x1 = rotl32(x1, 29); x1 ^= x0;
  x0 += x1; x1 = rotl32(x1, 16); x1 ^= x0;
  x0 += x1; x1 = rotl32(x1, 24); x1 ^= x0;
  x0 += k1; x1 += k2 + 4u;
  x0 += x1; x1 = rotl32(x1, 13); x1 ^= x0;
  x0 += x1; x1 = rotl32(x1, 15); x1 ^= x0;
  x0 += x1; x1 = rotl32(x1, 26); x1 ^= x0;
  x0 += x1; x1 = rotl32(x1,  6); x1 ^= x0;
  x0 += k2; x1 += k0 + 5u;
}

// Repack W [1024 rows][256 k] row-major -> [k][u][gate] (float4 per (k,u)).
__global__ void repack_k(const float* __restrict__ eWh,
                         const float* __restrict__ dWi,
                         const float* __restrict__ dWh,
                         float* __restrict__ ws) {
  float* encW4 = (float*)((char*)ws + WS_ENCW4_OFF);
  float* decWi4 = (float*)((char*)ws + WS_DECWI4_OFF);
  float* decWh4 = (float*)((char*)ws + WS_DECWH4_OFF);
  const int n = blockIdx.x * blockDim.x + threadIdx.x;   // 65536 = 256k x 256u
  if (n >= 65536) return;
  const int k = n >> 8, u = n & 255;
#pragma unroll
  for (int g = 0; g < 4; ++g) {
    const int src = ((g << 8) + u) * 256 + k;
    const int dst = (n << 2) + g;
    encW4[dst] = eWh[src];
    decWi4[dst] = dWi[src];
    decWh4[dst] = dWh[src];
  }
}

__global__ void __launch_bounds__(1024, 4)
ptrnet_kernel(const float* __restrict__ inp,    // [512][256][2]
              const float* __restrict__ eWi,    // [1024][2]
              const float* __restrict__ eBi, const float* __restrict__ eBh,
              const float* __restrict__ dBi, const float* __restrict__ dBh,
              int* __restrict__ out,            // [512][256]
              float* __restrict__ ws) {
  const int tid  = threadIdx.x;
  const int wave = tid >> 6, l = tid & 63;
  const int kq   = wave >> 2;               // K-quarter 0..3 (16 k4 each)
  const int uw   = wave & 3;                // u-slice 0..3
  const int uP   = (uw << 6) | l;           // this lane's unit in P1 (matmul)
  const int k4b  = kq << 4;
  const int bA   = tid >> 8;                // this thread's batch in P2/attn
  const int uA   = tid & 255;               // this thread's unit/score in P2/attn
  const int b0   = blockIdx.x << 2;
  const int bG   = b0 + bA;

  const v4f* encW4  = (const v4f*)((char*)ws + WS_ENCW4_OFF);
  const v4f* decWi4 = (const v4f*)((char*)ws + WS_DECWI4_OFF);
  const v4f* decWh4 = (const v4f*)((char*)ws + WS_DECWH4_OFF);
  v4f* encK4 = (v4f*)((char*)ws + WS_ENCK4_OFF);

  __shared__ __align__(16) float hsF[2][1024];   // h dbuf: [buf][b*256+u]
  __shared__ __align__(16) v4f dinV[256];        // dec_in [b][64 k4]
  __shared__ __align__(16) v4f red[16][256];     // partials [kq*4+b][u] (gates)
  __shared__ unsigned char maskC[4][256];
  __shared__ float partV[4][4];
  __shared__ int   partI[4][4];

  // ---- activation-thread constants (keyed by uA) ----
  const float ebi_ = eBi[uA] + eBh[uA];
  const float ebf_ = eBi[256 + uA] + eBh[256 + uA];
  const float ebg_ = eBi[512 + uA] + eBh[512 + uA];
  const float ebo_ = eBi[768 + uA] + eBh[768 + uA];
  const float wxi0 = eWi[2 * uA], wxi1 = eWi[2 * uA + 1];
  const float wxf0 = eWi[2 * (256 + uA)], wxf1 = eWi[2 * (256 + uA) + 1];
  const float wxg0 = eWi[2 * (512 + uA)], wxg1 = eWi[2 * (512 + uA) + 1];
  const float wxo0 = eWi[2 * (768 + uA)], wxo1 = eWi[2 * (768 + uA) + 1];

  hsF[0][tid] = 0.f;
  __syncthreads();

  float c = 0.f;        // cell state for (bG, uA) — register-resident throughout
  int p = 0;

  // ---------------- encoder: 256 steps (R4-exact) ----------------
  for (int t = 0; t < 256; ++t) {
    v4f a0 = (v4f)0.f, a1 = (v4f)0.f, a2 = (v4f)0.f, a3 = (v4f)0.f;
    const v4f* Wp = encW4 + uP;
    const v4f* hq = (const v4f*)&hsF[p][0];       // [4 b][64 k4]
#pragma unroll 2
    for (int kk = 0; kk < 16; ++kk) {
      const int k4 = k4b + kk;
      const v4f w0 = Wp[(k4 * 4 + 0) << 8];
      const v4f w1 = Wp[(k4 * 4 + 1) << 8];
      const v4f w2 = Wp[(k4 * 4 + 2) << 8];
      const v4f w3 = Wp[(k4 * 4 + 3) << 8];
      const v4f h0 = hq[k4];
      const v4f h1 = hq[64 + k4];
      const v4f h2 = hq[128 + k4];
      const v4f h3 = hq[192 + k4];
      a0 += w0 * h0.x + w1 * h0.y + w2 * h0.z + w3 * h0.w;
      a1 += w0 * h1.x + w1 * h1.y + w2 * h1.z + w3 * h1.w;
      a2 += w0 * h2.x + w1 * h2.y + w2 * h2.z + w3 * h2.w;
      a3 += w0 * h3.x + w1 * h3.y + w2 * h3.z + w3 * h3.w;
    }
    red[(kq << 2) | 0][uP] = a0;
    red[(kq << 2) | 1][uP] = a1;
    red[(kq << 2) | 2][uP] = a2;
    red[(kq << 2) | 3][uP] = a3;
    __syncthreads();                              // S_B: partials ready
    const v4f gv = red[bA][uA] + red[4 + bA][uA] + red[8 + bA][uA] + red[12 + bA][uA];
    const float2 xv = *(const float2*)(inp + (((bG) << 8) + t) * 2);
    const float ai = gv.x + ebi_ + wxi0 * xv.x + wxi1 * xv.y;
    const float af = gv.y + ebf_ + wxf0 * xv.x + wxf1 * xv.y;
    const float ag = gv.z + ebg_ + wxg0 * xv.x + wxg1 * xv.y;
    const float ao = gv.w + ebo_ + wxo0 * xv.x + wxo1 * xv.y;
    const float iv = sigm(ai), fv = sigm(af), gva = tanhf(ag), ov = sigm(ao);
    c = fv * c + iv * gva;
    const float hn = ov * tanhf(c);
    hsF[p ^ 1][(bA << 8) | uA] = hn;
    ((float*)encK4)[(((bG << 6) + (uA >> 2)) << 10) + (t << 2) + (uA & 3)] = hn;
    __syncthreads();                              // S_C: new h ready
    p ^= 1;
  }

  // ---------------- decoder: 256 steps, rotated schedule ----------------
  const float dbi_ = dBi[uA] + dBh[uA];
  const float dbf_ = dBi[256 + uA] + dBh[256 + uA];
  const float dbg_ = dBi[512 + uA] + dBh[512 + uA];
  const float dbo_ = dBi[768 + uA] + dBh[768 + uA];
  const float NEG_INF = __int_as_float((int)0xff800000);

  maskC[bA][uA] = 0;
  if (tid < 256) dinV[tid] = (v4f)0.f;
  __syncthreads();

  // ---- prologue: LSTM step 0 (din = 0 -> Wi contributes exact 0, skipped) ----
  {
    v4f a0 = (v4f)0.f, a1 = (v4f)0.f, a2 = (v4f)0.f, a3 = (v4f)0.f;
    const v4f* Wh = decWh4 + uP;
    const v4f* hq = (const v4f*)&hsF[p][0];
#pragma unroll 2
    for (int kk = 0; kk < 16; ++kk) {
      const int k4 = k4b + kk;
      const v4f w0 = Wh[(k4 * 4 + 0) << 8];
      const v4f w1 = Wh[(k4 * 4 + 1) << 8];
      const v4f w2 = Wh[(k4 * 4 + 2) << 8];
      const v4f w3 = Wh[(k4 * 4 + 3) << 8];
      const v4f h0 = hq[k4];
      const v4f h1 = hq[64 + k4];
      const v4f h2 = hq[128 + k4];
      const v4f h3 = hq[192 + k4];
      a0 += w0 * h0.x + w1 * h0.y + w2 * h0.z + w3 * h0.w;
      a1 += w0 * h1.x + w1 * h1.y + w2 * h1.z + w3 * h1.w;
      a2 += w0 * h2.x + w1 * h2.y + w2 * h2.z + w3 * h2.w;
      a3 += w0 * h3.x + w1 * h3.y + w2 * h3.z + w3 * h3.w;
    }
    red[(kq << 2) | 0][uP] = a0;
    red[(kq << 2) | 1][uP] = a1;
    red[(kq << 2) | 2][uP] = a2;
    red[(kq << 2) | 3][uP] = a3;
    __syncthreads();
    const v4f gv = red[bA][uA] + red[4 + bA][uA] + red[8 + bA][uA] + red[12 + bA][uA];
    const float iv = sigm(gv.x + dbi_), fv = sigm(gv.y + dbf_);
    const float gva = tanhf(gv.z + dbg_), ov = sigm(gv.w + dbo_);
    c = fv * c + iv * gva;
    const float hn = ov * tanhf(c);
    hsF[p ^ 1][(bA << 8) | uA] = hn;
    __syncthreads();
    p ^= 1;                                       // hsF[p] now holds h_0
  }

  for (int t = 0; t < 256; ++t) {
    // ---- overlap phase: attn(t) loads+consume  ∥  Wh·h_t sweep (for t+1) ----
    const int masked = maskC[bA][uA];
    const v4f* E   = encK4 + (bG << 14) + uA;     // s = uA, step u4 via <<8
    const v4f* hq  = (const v4f*)&hsF[p][0];
    const v4f* hq2 = hq + (bA << 6);
    const v4f* Wh  = decWh4 + uP;
    v4f a0 = (v4f)0.f, a1 = (v4f)0.f, a2 = (v4f)0.f, a3 = (v4f)0.f;
    float sc = 0.f;
    v4f eA[3][4];                                  // 3 chunks x 4 k4 in flight
    if (!masked) {
#pragma unroll
      for (int j = 0; j < 4; ++j) eA[0][j] = E[j << 8];
#pragma unroll
      for (int j = 0; j < 4; ++j) eA[1][j] = E[(4 + j) << 8];
    }
#pragma unroll
    for (int ph = 0; ph < 16; ++ph) {
      // Wh iteration kk = ph (same expression/order as R4 -> bit-identical a)
      {
        const int k4 = k4b + ph;
        const v4f w0 = Wh[(k4 * 4 + 0) << 8];
        const v4f w1 = Wh[(k4 * 4 + 1) << 8];
        const v4f w2 = Wh[(k4 * 4 + 2) << 8];
        const v4f w3 = Wh[(k4 * 4 + 3) << 8];
        const v4f h0 = hq[k4];
        const v4f h1 = hq[64 + k4];
        const v4f h2 = hq[128 + k4];
        const v4f h3 = hq[192 + k4];
        a0 += w0 * h0.x + w1 * h0.y + w2 * h0.z + w3 * h0.w;
        a1 += w0 * h1.x + w1 * h1.y + w2 * h1.z + w3 * h1.w;
        a2 += w0 * h2.x + w1 * h2.y + w2 * h2.z + w3 * h2.w;
        a3 += w0 * h3.x + w1 * h3.y + w2 * h3.z + w3 * h3.w;
      }
      // issue attn chunk ph+2
      if (ph < 14) {
        if (!masked) {
#pragma unroll
          for (int j = 0; j < 4; ++j) eA[(ph + 2) % 3][j] = E[((ph + 2) * 4 + j) << 8];
        }
      }
      // consume attn chunk ph (sc chain order identical to R4's k4 order)
      if (!masked) {
#pragma unroll
        for (int j = 0; j < 4; ++j) {
          const int k4 = ph * 4 + j;
          const v4f ev = eA[ph % 3][j];
          const v4f hv = hq2[k4];
          sc += ev.x * hv.x + ev.y * hv.y + ev.z * hv.z + ev.w * hv.w;
        }
      }
    }

    // ---- gumbel + argmax (thread (bA, s=uA)) ----
    unsigned bits;
    {
      unsigned kk0 = 0u, kk1 = (unsigned)t;
      tf2(0u, 42u, kk0, kk1);
      unsigned y0 = 0u, y1 = (unsigned)((bG << 8) + uA);
      tf2(kk0, kk1, y0, y1);
      bits = y0 ^ y1;
    }
    const float fr = __uint_as_float((bits >> 9) | 0x3f800000u) - 1.0f;
    const float uu = (fr > 0.f) ? fr : 1.17549435e-38f;
    const float gum = -logf(-logf(uu));
    float bv = masked ? NEG_INF : (sc + gum);
    int bi = uA;
#pragma unroll
    for (int off = 32; off; off >>= 1) {
      const float ov2 = __shfl_xor(bv, off, 64);
      const int oi2 = __shfl_xor(bi, off, 64);
      if (ov2 > bv || (ov2 == bv && oi2 < bi)) { bv = ov2; bi = oi2; }
    }
    if (l == 0) { partV[bA][uw] = bv; partI[bA][uw] = bi; }
    __syncthreads();                              // S_D: wave partials ready

    // final cross-chunk argmax, recomputed redundantly per thread
    float v = partV[bA][0]; int fi = partI[bA][0];
#pragma unroll
    for (int j = 1; j < 4; ++j) {
      const float vj = partV[bA][j];
      if (vj > v) { v = vj; fi = partI[bA][j]; }   // strict > keeps lowest s
    }
    if (uA == 0) out[(bG << 8) + t] = fi;
    if (uA == fi) maskC[bA][uA] = 1;
    if (tid < 256) {                               // stage din_{t+1}
      const int bb = tid >> 6, k4s = tid & 63;
      float v2 = partV[bb][0]; int fib = partI[bb][0];
#pragma unroll
      for (int j = 1; j < 4; ++j) {
        const float vj = partV[bb][j];
        if (vj > v2) { v2 = vj; fib = partI[bb][j]; }
      }
      dinV[tid] = encK4[((((b0 + bb) << 6) | k4s) << 8) + fib];
    }
    __syncthreads();                              // S_A: din/mask ready

    if (t == 255) break;                           // last index emitted

    // ---- Wi·din sweep (adds into the SAME a-regs, R4 order) ----
    {
      const v4f* Wi = decWi4 + uP;
#pragma unroll 2
      for (int kk = 0; kk < 16; ++kk) {
        const int k4 = k4b + kk;
        const v4f w0 = Wi[(k4 * 4 + 0) << 8];
        const v4f w1 = Wi[(k4 * 4 + 1) << 8];
        const v4f w2 = Wi[(k4 * 4 + 2) << 8];
        const v4f w3 = Wi[(k4 * 4 + 3) << 8];
        const v4f d0 = dinV[k4];
        const v4f d1 = dinV[64 + k4];
        const v4f d2 = dinV[128 + k4];
        const v4f d3 = dinV[192 + k4];
        a0 += w0 * d0.x + w1 * d0.y + w2 * d0.z + w3 * d0.w;
        a1 += w0 * d1.x + w1 * d1.y + w2 * d1.z + w3 * d1.w;
        a2 += w0 * d2.x + w1 * d2.y + w2 * d2.z + w3 * d2.w;
        a3 += w0 * d3.x + w1 * d3.y + w2 * d3.z + w3 * d3.w;
      }
    }
    red[(kq << 2) | 0][uP] = a0;
    red[(kq << 2) | 1][uP] = a1;
    red[(kq << 2) | 2][uP] = a2;
    red[(kq << 2) | 3][uP] = a3;
    __syncthreads();                              // S_B: partials ready

    // ---- P2: activation -> h_{t+1} ----
    const v4f gv = red[bA][uA] + red[4 + bA][uA] + red[8 + bA][uA] + red[12 + bA][uA];
    const float iv = sigm(gv.x + dbi_), fv = sigm(gv.y + dbf_);
    const float gva = tanhf(gv.z + dbg_), ov = sigm(gv.w + dbo_);
    c = fv * c + iv * gva;
    const float hn = ov * tanhf(c);
    hsF[p ^ 1][(bA << 8) | uA] = hn;
    __syncthreads();                              // S_C: new h ready
    p ^= 1;
  }
}

extern "C" void kernel_launch(void* const* d_in, const int* in_sizes, int n_in,
                              void* d_out, int out_size, void* d_ws, size_t ws_size,
                              hipStream_t stream) {
  (void)in_sizes; (void)n_in; (void)out_size;
  if (ws_size < WS_NEEDED) return;   // need ~139 MB scratch

  const float* inp = (const float*)d_in[0];
  const float* eWi = (const float*)d_in[1];
  const float* eWh = (const float*)d_in[2];
  const float* eBi = (const float*)d_in[3];
  const float* eBh = (const float*)d_in[4];
  const float* dWi = (const float*)d_in[5];
  const float* dWh = (const float*)d_in[6];
  const float* dBi = (const float*)d_in[7];
  const float* dBh = (const float*)d_in[8];
  int* out = (int*)d_out;
  float* wsf = (float*)d_ws;

  hipLaunchKernelGGL(repack_k, dim3(256), dim3(256), 0, stream, eWh, dWi, dWh, wsf);
  hipLaunchKernelGGL(ptrnet_kernel, dim3(128), dim3(1024), 0, stream,
                     inp, eWi, eBi, eBh, dBi, dBh, out, wsf);
}